// Round 7
// baseline (861.177 us; speedup 1.0000x reference)
//
#include <hip/hip_runtime.h>
#include <hip/hip_bf16.h>
#include <math.h>

#define TOKENS 8192
#define DMODEL 1024
#define DFF    4096
#define NEXP   8
#define PAD_IDX   17664   // token_ids/pair_p entries (16384 + 8*128 pad + 256-tile overhang)
#define PAD_H     17664   // h rows allocated
#define MAX_SLOTS 72      // sum ceil(c_e/256) <= 16384/256 + 8 = 72
#define BK 64

typedef __bf16 bf16;
typedef bf16  bf16x8 __attribute__((ext_vector_type(8)));
typedef float f32x4  __attribute__((ext_vector_type(4)));

// async global->LDS, 16B per lane. LDS dest must be wave-uniform; HW adds lane*16.
__device__ __forceinline__ void gload16(const bf16* g, bf16* l) {
    __builtin_amdgcn_global_load_lds(
        (const __attribute__((address_space(1))) void*)g,
        (__attribute__((address_space(3))) void*)l,
        16, 0, 0);
}

// ---------------- gating: one wave per token (also emits xb = bf16(x)) -----
__global__ __launch_bounds__(256) void gate_kernel(
    const float* __restrict__ x, const float* __restrict__ gw, const float* __restrict__ gb,
    int* __restrict__ counts, int2* __restrict__ topk_i, float2* __restrict__ topk_p,
    bf16* __restrict__ xb)
{
    int wid  = (blockIdx.x * blockDim.x + threadIdx.x) >> 6;   // token id
    int lane = threadIdx.x & 63;
    if (wid >= TOKENS) return;
    const float* xr = x + (size_t)wid * DMODEL;
    bf16* xbr = xb + (size_t)wid * DMODEL;
    float a0=0,a1=0,a2=0,a3=0,a4=0,a5=0,a6=0,a7=0;
    #pragma unroll
    for (int i = 0; i < DMODEL/64; ++i) {
        int d = lane + (i << 6);
        float xv = xr[d];
        xbr[d] = (bf16)xv;
        const float4* g = (const float4*)(gw + (size_t)d * NEXP);
        float4 g0 = g[0], g1 = g[1];
        a0 += xv * g0.x; a1 += xv * g0.y; a2 += xv * g0.z; a3 += xv * g0.w;
        a4 += xv * g1.x; a5 += xv * g1.y; a6 += xv * g1.z; a7 += xv * g1.w;
    }
    #pragma unroll
    for (int off = 32; off; off >>= 1) {
        a0 += __shfl_xor(a0, off); a1 += __shfl_xor(a1, off);
        a2 += __shfl_xor(a2, off); a3 += __shfl_xor(a3, off);
        a4 += __shfl_xor(a4, off); a5 += __shfl_xor(a5, off);
        a6 += __shfl_xor(a6, off); a7 += __shfl_xor(a7, off);
    }
    float l[NEXP] = { a0+gb[0], a1+gb[1], a2+gb[2], a3+gb[3],
                      a4+gb[4], a5+gb[5], a6+gb[6], a7+gb[7] };
    float m = l[0];
    #pragma unroll
    for (int e = 1; e < NEXP; ++e) m = fmaxf(m, l[e]);
    float p[NEXP], s = 0.f;
    #pragma unroll
    for (int e = 0; e < NEXP; ++e) { p[e] = expf(l[e] - m); s += p[e]; }
    float inv = 1.0f / s;
    int i1 = 0; float b1v = p[0];
    #pragma unroll
    for (int e = 1; e < NEXP; ++e) if (p[e] > b1v) { b1v = p[e]; i1 = e; }
    int i2 = -1; float b2v = -1.f;
    #pragma unroll
    for (int e = 0; e < NEXP; ++e) if (e != i1 && p[e] > b2v) { b2v = p[e]; i2 = e; }
    if (lane == 0) {
        topk_i[wid] = make_int2(i1, i2);
        topk_p[wid] = make_float2(b1v * inv, b2v * inv);
        atomicAdd(&counts[i1], 1);
        atomicAdd(&counts[i2], 1);
    }
}

// ---------------- routing tables (parallel; scan kept in LDS/regs) ---------
__global__ void build_slots(const int* __restrict__ counts, int* seg_base, int* n_slots,
                            int* slot_e, int* slot_row0, int* slot_gbase)
{
    __shared__ int sc[8], spb[9], stb[9];
    int t = threadIdx.x;                       // 128 threads, 1 block
    if (t < 8) sc[t] = counts[t];
    __syncthreads();
    if (t == 0) {
        int pb = 0, tb = 0;
        for (int e = 0; e < NEXP; ++e) {
            spb[e] = pb; stb[e] = tb;
            pb += ((sc[e] + 127) >> 7) << 7;   // 128-padded segment bases
            tb += (sc[e] + 255) >> 8;          // 256-row tile counts
        }
        spb[8] = pb; stb[8] = tb;
        *n_slots = tb;
    }
    __syncthreads();
    if (t < 8) seg_base[t] = spb[t];
    int ns = stb[8];
    if (t < ns) {
        int e = 0;
        while (t >= stb[e + 1]) ++e;
        slot_e[t] = e;
        slot_row0[t] = (t - stb[e]) << 8;
        slot_gbase[t] = spb[e];
    }
}

__global__ __launch_bounds__(256) void scatter_kernel(
    const int2* __restrict__ topk_i, const float2* __restrict__ topk_p,
    const int* __restrict__ seg_base, int* __restrict__ cursor,
    int* __restrict__ token_ids, float* __restrict__ pair_p)
{
    int t = blockIdx.x * 256 + threadIdx.x;
    if (t >= TOKENS) return;
    int2 ki = topk_i[t]; float2 kp = topk_p[t];
    int p0 = seg_base[ki.x] + atomicAdd(&cursor[ki.x], 1);
    token_ids[p0] = t; pair_p[p0] = kp.x;
    int p1 = seg_base[ki.y] + atomicAdd(&cursor[ki.y], 1);
    token_ids[p1] = t; pair_p[p1] = kp.y;
}

// ---------------- fp32 [E][R][C] -> bf16 [E][C][R], 64x64 tiles, vectorized -
// loads: 4x float4 / thread; LDS bf16 [64][72] (144B rows, 16B-aligned);
// stores: 2x b128 / thread (128B contiguous per 4-lane column group).
__global__ __launch_bounds__(256) void transpose_cvt(
    const float* __restrict__ src, bf16* __restrict__ dst, int R, int C)
{
    __shared__ bf16 tile[64][72];
    int e = blockIdx.z;
    int c0 = blockIdx.x * 64, r0 = blockIdx.y * 64;
    const float* s = src + (size_t)e * R * C;
    bf16* d = dst + (size_t)e * R * C;
    int t = threadIdx.x;
    {
        int r = t >> 2, cs = (t & 3) * 16;
        const float4* s4 = (const float4*)(s + (size_t)(r0 + r) * C + c0 + cs);
        float4 v0 = s4[0], v1 = s4[1], v2 = s4[2], v3 = s4[3];
        bf16x8 p0, p1;
        p0[0]=(bf16)v0.x; p0[1]=(bf16)v0.y; p0[2]=(bf16)v0.z; p0[3]=(bf16)v0.w;
        p0[4]=(bf16)v1.x; p0[5]=(bf16)v1.y; p0[6]=(bf16)v1.z; p0[7]=(bf16)v1.w;
        p1[0]=(bf16)v2.x; p1[1]=(bf16)v2.y; p1[2]=(bf16)v2.z; p1[3]=(bf16)v2.w;
        p1[4]=(bf16)v3.x; p1[5]=(bf16)v3.y; p1[6]=(bf16)v3.z; p1[7]=(bf16)v3.w;
        *(bf16x8*)&tile[r][cs] = p0;
        *(bf16x8*)&tile[r][cs + 8] = p1;
    }
    __syncthreads();
    {
        int c = t >> 2, rs = (t & 3) * 16;
        bf16x8 q0, q1;
        #pragma unroll
        for (int k = 0; k < 8; ++k) { q0[k] = tile[rs + k][c]; q1[k] = tile[rs + 8 + k][c]; }
        *(bf16x8*)(d + (size_t)(c0 + c) * R + r0 + rs) = q0;
        *(bf16x8*)(d + (size_t)(c0 + c) * R + r0 + rs + 8) = q1;
    }
}

// ---------------- grouped GEMM: 256x256 tile, 8 waves, 8-phase counted-vmcnt -
// (structure identical to r6 - verified ledger; only KSPL for MODE1 changed)
template<int MODE>
__global__ __launch_bounds__(512, 2) void moe_gemm(
    const bf16* __restrict__ Xb, const bf16* __restrict__ Ah,
    const bf16* __restrict__ Bt, const float* __restrict__ bias,
    bf16* __restrict__ Hout, float* __restrict__ Out,
    const int* __restrict__ token_ids, const float* __restrict__ pair_p,
    const int* __restrict__ slot_e, const int* __restrict__ slot_row0,
    const int* __restrict__ slot_gbase, const int* __restrict__ n_slots,
    const int* __restrict__ counts)
{
    constexpr int K    = (MODE == 0) ? DMODEL : DFF;
    constexpr int N    = (MODE == 0) ? DFF : DMODEL;
    constexpr int NJT  = N / 256;
    constexpr int KSPL = (MODE == 0) ? 1 : 4;
    constexpr int KCH  = K / KSPL;
    constexpr int NT   = KCH / BK;               // 16 (even)
    constexpr int NITER = NT / 2;

    int nwg = gridDim.x;                         // multiple of 8
    int bid = blockIdx.x;
    int wid = (bid & 7) * (nwg >> 3) + (bid >> 3);
    int slot = wid / (NJT * KSPL);
    if (slot >= *n_slots) return;
    int rem = wid % (NJT * KSPL);
    int jt = rem / KSPL, split = rem % KSPL;
    int kbase = split * KCH;

    int e = slot_e[slot], row0 = slot_row0[slot], gbase = slot_gbase[slot];
    int cnt = counts[e];
    int pad_e = (cnt + 127) & ~127;

    __shared__ __align__(16) bf16 shm[65536];    // A: [0,32768) B: [32768,65536)

    int t = threadIdx.x;
    int lane = t & 63, wv = t >> 6;
    int wm = wv >> 2, wn = wv & 3;
    int lr = lane & 15, kq = lane >> 4;
    int bh = wn >> 1, bro = (wn & 1) * 64;

    // staging source offsets (elems), per (half, q-instr):
    //   row_local = wv*16 + q*8 + lane/8; granule g = (lane&7)^(lane>>3)
    int aoff[2][2]; int boff[2][2];
    const bf16* Abase = (MODE == 0) ? Xb : Ah;
    const bf16* Bbase = Bt + (size_t)e * N * K;
    int g8 = ((lane & 7) ^ (lane >> 3)) * 8;
    #pragma unroll
    for (int h = 0; h < 2; ++h)
        #pragma unroll
        for (int q = 0; q < 2; ++q) {
            int rloc = h*128 + wv*16 + q*8 + (lane >> 3);
            if (MODE == 0) {
                int tok = token_ids[gbase + row0 + rloc];
                aoff[h][q] = tok * DMODEL + g8;
            } else {
                aoff[h][q] = (gbase + row0 + rloc) * DFF + kbase + g8;
            }
            boff[h][q] = (jt*256 + rloc) * K + kbase + g8;
        }

    f32x4 acc[8][4] = {};
    bf16x8 breg[4][2];

    #define STAGE_A(S, H, T) do { int _t = ((T) < NT ? (T) : 0) * BK;                   \
        gload16(Abase + aoff[H][0] + _t, shm + (((S)*2+(H))*128 + wv*16    ) * BK);     \
        gload16(Abase + aoff[H][1] + _t, shm + (((S)*2+(H))*128 + wv*16 + 8) * BK); } while(0)
    #define STAGE_B(S, H, T) do { int _t = ((T) < NT ? (T) : 0) * BK;                           \
        gload16(Bbase + boff[H][0] + _t, shm + 32768 + (((S)*2+(H))*128 + wv*16    ) * BK);     \
        gload16(Bbase + boff[H][1] + _t, shm + 32768 + (((S)*2+(H))*128 + wv*16 + 8) * BK); } while(0)

    // prologue: T0 all 4 halves, T1 B halves; vmcnt(4) certifies T0 landed
    STAGE_A(0,0,0); STAGE_A(0,1,0); STAGE_B(0,0,0); STAGE_B(0,1,0);
    STAGE_B(1,0,1); STAGE_B(1,1,1);
    asm volatile("s_waitcnt vmcnt(4)" ::: "memory");
    __builtin_amdgcn_s_barrier();

    #define PHASE(S, Q, STAGE_CODE, DO_WAIT)                                         \
    {                                                                                \
        bf16x8 areg[2][2];                                                           \
        if ((Q) == 0) {                                                              \
            _Pragma("unroll") for (int n = 0; n < 4; ++n)                            \
                _Pragma("unroll") for (int kk = 0; kk < 2; ++kk)                     \
                    breg[n][kk] = *(const bf16x8*)(shm + 32768 +                     \
                        (((S)*2+bh)*128 + bro + n*16 + lr) * BK +                    \
                        ((kk*4+kq) ^ (lr & 7)) * 8);                                 \
        }                                                                            \
        _Pragma("unroll") for (int mi = 0; mi < 2; ++mi)                             \
            _Pragma("unroll") for (int kk = 0; kk < 2; ++kk)                         \
                areg[mi][kk] = *(const bf16x8*)(shm +                                \
                    (((S)*2+wm)*128 + ((Q)*2+mi)*16 + lr) * BK +                     \
                    ((kk*4+kq) ^ (lr & 7)) * 8);                                     \
        STAGE_CODE;                                                                  \
        asm volatile("" ::: "memory");                                               \
        __builtin_amdgcn_s_barrier();                                                \
        __builtin_amdgcn_s_setprio(1);                                               \
        _Pragma("unroll") for (int mi = 0; mi < 2; ++mi)                             \
            _Pragma("unroll") for (int n = 0; n < 4; ++n)                            \
                _Pragma("unroll") for (int kk = 0; kk < 2; ++kk)                     \
                    acc[(Q)*2+mi][n] = __builtin_amdgcn_mfma_f32_16x16x32_bf16(      \
                        areg[mi][kk], breg[n][kk], acc[(Q)*2+mi][n], 0, 0, 0);       \
        __builtin_amdgcn_s_setprio(0);                                               \
        if (DO_WAIT) asm volatile("s_waitcnt vmcnt(4)" ::: "memory");                \
        asm volatile("" ::: "memory");                                               \
        __builtin_amdgcn_s_barrier();                                                \
    }

    for (int i = 0; i < NITER; ++i) {
        int TO = 2*i+1, TE2 = 2*i+2, TO2 = 2*i+3;
        PHASE(0, 0, STAGE_A(1,0,TO),  0)
        PHASE(0, 1, STAGE_A(1,1,TO),  0)
        PHASE(0, 2, STAGE_B(0,0,TE2), 0)
        PHASE(0, 3, STAGE_B(0,1,TE2), 1)
        PHASE(1, 0, STAGE_A(0,0,TE2), 0)
        PHASE(1, 1, STAGE_A(0,1,TE2), 0)
        PHASE(1, 2, STAGE_B(1,0,TO2), 0)
        PHASE(1, 3, STAGE_B(1,1,TO2), 1)
    }
    asm volatile("s_waitcnt vmcnt(0)" ::: "memory");   // drain tail junk stages
    #undef PHASE
    #undef STAGE_A
    #undef STAGE_B

    int lro = kq * 4;
    if (MODE == 0) {
        float bv[4];
        #pragma unroll
        for (int n = 0; n < 4; ++n)
            bv[n] = bias[e * DFF + jt*256 + wn*64 + n*16 + lr];
        #pragma unroll
        for (int m = 0; m < 8; ++m)
            #pragma unroll
            for (int reg = 0; reg < 4; ++reg) {
                int rl = wm*128 + m*16 + lro + reg;
                if (row0 + rl < pad_e) {
                    size_t hrow = (size_t)(gbase + row0 + rl);
                    #pragma unroll
                    for (int n = 0; n < 4; ++n) {
                        int col = jt*256 + wn*64 + n*16 + lr;
                        float v = acc[m][n][reg] + bv[n];
                        v = v / (1.0f + __expf(-v));       // silu
                        Hout[hrow * DFF + col] = (bf16)v;
                    }
                }
            }
    } else {
        float bv[4];
        #pragma unroll
        for (int n = 0; n < 4; ++n)
            bv[n] = (split == 0) ? bias[e * DMODEL + jt*256 + wn*64 + n*16 + lr] : 0.0f;
        #pragma unroll
        for (int m = 0; m < 8; ++m)
            #pragma unroll
            for (int reg = 0; reg < 4; ++reg) {
                int rl = wm*128 + m*16 + lro + reg;
                if (row0 + rl < cnt) {
                    int pr = gbase + row0 + rl;
                    int tok = token_ids[pr];
                    float p = pair_p[pr];
                    #pragma unroll
                    for (int n = 0; n < 4; ++n) {
                        int col = jt*256 + wn*64 + n*16 + lr;
                        atomicAdd(Out + (size_t)tok * DMODEL + col, p * (acc[m][n][reg] + bv[n]));
                    }
                }
            }
    }
}

// ---------------- launch ----------------
extern "C" void kernel_launch(void* const* d_in, const int* in_sizes, int n_in,
                              void* d_out, int out_size, void* d_ws, size_t ws_size,
                              hipStream_t stream)
{
    const float* x  = (const float*)d_in[0];
    const float* gw = (const float*)d_in[1];
    const float* gb = (const float*)d_in[2];
    const float* w1 = (const float*)d_in[3];
    const float* b1 = (const float*)d_in[4];
    const float* w2 = (const float*)d_in[5];
    const float* b2 = (const float*)d_in[6];
    float* out = (float*)d_out;

    const size_t W1T_OFF = 0;
    const size_t W2T_OFF = 67108864;                       // 8*4096*1024*2
    const size_t H_OFF   = 134217728;
    const size_t RT_OFF  = H_OFF + (size_t)PAD_H * DFF * 2; // 278921216
    const size_t WS_NEEDED = RT_OFF + 274432;               // 279195648
    if (ws_size < WS_NEEDED) return;                        // fail clean

    char* ws = (char*)d_ws;
    bf16* w1t = (bf16*)(ws + W1T_OFF);
    bf16* w2t = (bf16*)(ws + W2T_OFF);
    bf16* xb  = (bf16*)(ws + W2T_OFF);          // aliases w2t: xb dead after gemm1
    bf16* h   = (bf16*)(ws + H_OFF);
    char* rt  = ws + RT_OFF;
    int*   counts    = (int*)(rt + 0);
    int*   seg_base  = (int*)(rt + 64);
    int*   cursor    = (int*)(rt + 128);
    int*   n_slots   = (int*)(rt + 192);
    int*   slot_e    = (int*)(rt + 256);
    int*   slot_row0 = (int*)(rt + 768);
    int*   slot_gbase= (int*)(rt + 1280);
    int2*  topk_i    = (int2*)(rt + 2048);
    float2* topk_p   = (float2*)(rt + 67584);
    int*   token_ids = (int*)(rt + 133120);
    float* pair_p    = (float*)(rt + 203776);

    hipMemsetAsync(rt, 0, 256, stream);                           // counts/cursor/n_slots
    hipMemsetAsync(token_ids, 0, PAD_IDX * sizeof(int), stream);
    hipMemsetAsync(out, 0, (size_t)TOKENS * DMODEL * sizeof(float), stream);

    transpose_cvt<<<dim3(DFF/64, DMODEL/64, NEXP), dim3(256), 0, stream>>>(w1, w1t, DMODEL, DFF);

    gate_kernel<<<TOKENS * 64 / 256, 256, 0, stream>>>(x, gw, gb, counts, topk_i, topk_p, xb);
    build_slots<<<1, 128, 0, stream>>>(counts, seg_base, n_slots, slot_e, slot_row0, slot_gbase);
    scatter_kernel<<<TOKENS / 256, 256, 0, stream>>>(topk_i, topk_p, seg_base, cursor, token_ids, pair_p);

    moe_gemm<0><<<MAX_SLOTS * (DFF/256), 512, 0, stream>>>(
        xb, nullptr, w1t, b1, h, nullptr,
        token_ids, pair_p, slot_e, slot_row0, slot_gbase, n_slots, counts);

    // w2 transpose AFTER gemm1 so w2t can alias xb
    transpose_cvt<<<dim3(DMODEL/64, DFF/64, NEXP), dim3(256), 0, stream>>>(w2, w2t, DFF, DMODEL);

    moe_gemm<1><<<MAX_SLOTS * (DMODEL/256) * 4, 512, 0, stream>>>(
        nullptr, h, w2t, b2, nullptr, out,
        token_ids, pair_p, slot_e, slot_row0, slot_gbase, n_slots, counts);
}

// Round 8
// 783.303 us; speedup vs baseline: 1.0994x; 1.0994x over previous
//
#include <hip/hip_runtime.h>
#include <hip/hip_bf16.h>
#include <math.h>

#define TOKENS 8192
#define DMODEL 1024
#define DFF    4096
#define NEXP   8
#define PAD_IDX   17664   // token_ids/pair_p entries (16384 + 8*128 pad + 256-tile overhang)
#define PAD_H     17664   // h rows allocated
#define MAX_SLOTS 72      // sum ceil(c_e/256) <= 16384/256 + 8 = 72
#define BK 64

typedef __bf16 bf16;
typedef bf16  bf16x8 __attribute__((ext_vector_type(8)));
typedef float f32x4  __attribute__((ext_vector_type(4)));

// async global->LDS, 16B per lane. LDS dest must be wave-uniform; HW adds lane*16.
__device__ __forceinline__ void gload16(const bf16* g, bf16* l) {
    __builtin_amdgcn_global_load_lds(
        (const __attribute__((address_space(1))) void*)g,
        (__attribute__((address_space(3))) void*)l,
        16, 0, 0);
}

// ---------------- gating: one wave per token (also emits xb = bf16(x)) -----
__global__ __launch_bounds__(256) void gate_kernel(
    const float* __restrict__ x, const float* __restrict__ gw, const float* __restrict__ gb,
    int* __restrict__ counts, int2* __restrict__ topk_i, float2* __restrict__ topk_p,
    bf16* __restrict__ xb)
{
    int wid  = (blockIdx.x * blockDim.x + threadIdx.x) >> 6;   // token id
    int lane = threadIdx.x & 63;
    if (wid >= TOKENS) return;
    const float* xr = x + (size_t)wid * DMODEL;
    bf16* xbr = xb + (size_t)wid * DMODEL;
    float a0=0,a1=0,a2=0,a3=0,a4=0,a5=0,a6=0,a7=0;
    #pragma unroll
    for (int i = 0; i < DMODEL/64; ++i) {
        int d = lane + (i << 6);
        float xv = xr[d];
        xbr[d] = (bf16)xv;
        const float4* g = (const float4*)(gw + (size_t)d * NEXP);
        float4 g0 = g[0], g1 = g[1];
        a0 += xv * g0.x; a1 += xv * g0.y; a2 += xv * g0.z; a3 += xv * g0.w;
        a4 += xv * g1.x; a5 += xv * g1.y; a6 += xv * g1.z; a7 += xv * g1.w;
    }
    #pragma unroll
    for (int off = 32; off; off >>= 1) {
        a0 += __shfl_xor(a0, off); a1 += __shfl_xor(a1, off);
        a2 += __shfl_xor(a2, off); a3 += __shfl_xor(a3, off);
        a4 += __shfl_xor(a4, off); a5 += __shfl_xor(a5, off);
        a6 += __shfl_xor(a6, off); a7 += __shfl_xor(a7, off);
    }
    float l[NEXP] = { a0+gb[0], a1+gb[1], a2+gb[2], a3+gb[3],
                      a4+gb[4], a5+gb[5], a6+gb[6], a7+gb[7] };
    float m = l[0];
    #pragma unroll
    for (int e = 1; e < NEXP; ++e) m = fmaxf(m, l[e]);
    float p[NEXP], s = 0.f;
    #pragma unroll
    for (int e = 0; e < NEXP; ++e) { p[e] = expf(l[e] - m); s += p[e]; }
    float inv = 1.0f / s;
    int i1 = 0; float b1v = p[0];
    #pragma unroll
    for (int e = 1; e < NEXP; ++e) if (p[e] > b1v) { b1v = p[e]; i1 = e; }
    int i2 = -1; float b2v = -1.f;
    #pragma unroll
    for (int e = 0; e < NEXP; ++e) if (e != i1 && p[e] > b2v) { b2v = p[e]; i2 = e; }
    if (lane == 0) {
        topk_i[wid] = make_int2(i1, i2);
        topk_p[wid] = make_float2(b1v * inv, b2v * inv);
        atomicAdd(&counts[i1], 1);
        atomicAdd(&counts[i2], 1);
    }
}

// ---------------- routing tables (parallel; scan kept in LDS/regs) ---------
__global__ void build_slots(const int* __restrict__ counts, int* seg_base, int* n_slots,
                            int* slot_e, int* slot_row0, int* slot_gbase)
{
    __shared__ int sc[8], spb[9], stb[9];
    int t = threadIdx.x;                       // 128 threads, 1 block
    if (t < 8) sc[t] = counts[t];
    __syncthreads();
    if (t == 0) {
        int pb = 0, tb = 0;
        for (int e = 0; e < NEXP; ++e) {
            spb[e] = pb; stb[e] = tb;
            pb += ((sc[e] + 127) >> 7) << 7;   // 128-padded segment bases
            tb += (sc[e] + 255) >> 8;          // 256-row tile counts
        }
        spb[8] = pb; stb[8] = tb;
        *n_slots = tb;
    }
    __syncthreads();
    if (t < 8) seg_base[t] = spb[t];
    int ns = stb[8];
    if (t < ns) {
        int e = 0;
        while (t >= stb[e + 1]) ++e;
        slot_e[t] = e;
        slot_row0[t] = (t - stb[e]) << 8;
        slot_gbase[t] = spb[e];
    }
}

__global__ __launch_bounds__(256) void scatter_kernel(
    const int2* __restrict__ topk_i, const float2* __restrict__ topk_p,
    const int* __restrict__ seg_base, int* __restrict__ cursor,
    int* __restrict__ token_ids, float* __restrict__ pair_p)
{
    int t = blockIdx.x * 256 + threadIdx.x;
    if (t >= TOKENS) return;
    int2 ki = topk_i[t]; float2 kp = topk_p[t];
    int p0 = seg_base[ki.x] + atomicAdd(&cursor[ki.x], 1);
    token_ids[p0] = t; pair_p[p0] = kp.x;
    int p1 = seg_base[ki.y] + atomicAdd(&cursor[ki.y], 1);
    token_ids[p1] = t; pair_p[p1] = kp.y;
}

// ---------------- fp32 [E][R][C] -> bf16 [E][C][R], 64x64 tiles ------------
// (r6-proven: f32 LDS [64][65] -> 2-way conflicts only; r7's bf16[64][72] had 8-way)
__global__ __launch_bounds__(256) void transpose_cvt(
    const float* __restrict__ src, bf16* __restrict__ dst, int R, int C)
{
    __shared__ float tile[64][65];
    int e = blockIdx.z;
    int c0 = blockIdx.x * 64, r0 = blockIdx.y * 64;
    const float* s = src + (size_t)e * R * C;
    bf16* d = dst + (size_t)e * R * C;
    int tx = threadIdx.x, ty = threadIdx.y;     // 64, 4
    #pragma unroll
    for (int k = 0; k < 16; ++k)
        tile[ty + 4*k][tx] = s[(size_t)(r0 + ty + 4*k) * C + c0 + tx];
    __syncthreads();
    #pragma unroll
    for (int k = 0; k < 16; ++k)
        d[(size_t)(c0 + ty + 4*k) * R + r0 + tx] = (bf16)tile[tx][ty + 4*k];
}

// ---------------- grouped GEMM: 256x256 tile, 8 waves, merged 4-phase iter --
// MODE 0: h = silu(xb[gather] @ w1t^T + b1)   (K=1024, N=4096)
// MODE 1: out[token] += p*(h @ w2t^T + b2)    (K=4096 split 2, N=1024), atomicAdd
// r6's verified ledger, but phase PAIRS merged: one barrier pair per 32 MFMA
// (2 quadrant sub-steps per phase; sub-step boundary needs no barrier: same
// certified slot, stages only touch the other slot). vmcnt(4) ledger identical
// in instruction counts: prologue 12 -> drain 8; each merged B-stage phase ends
// vmcnt(4) draining exactly the 8 loads of the slot needed next.
template<int MODE>
__global__ __launch_bounds__(512, 2) void moe_gemm(
    const bf16* __restrict__ Xb, const bf16* __restrict__ Ah,
    const bf16* __restrict__ Bt, const float* __restrict__ bias,
    bf16* __restrict__ Hout, float* __restrict__ Out,
    const int* __restrict__ token_ids, const float* __restrict__ pair_p,
    const int* __restrict__ slot_e, const int* __restrict__ slot_row0,
    const int* __restrict__ slot_gbase, const int* __restrict__ n_slots,
    const int* __restrict__ counts)
{
    constexpr int K    = (MODE == 0) ? DMODEL : DFF;
    constexpr int N    = (MODE == 0) ? DFF : DMODEL;
    constexpr int NJT  = N / 256;
    constexpr int KSPL = (MODE == 0) ? 1 : 2;
    constexpr int KCH  = K / KSPL;
    constexpr int NT   = KCH / BK;               // 16 or 32 (even)
    constexpr int NITER = NT / 2;

    int nwg = gridDim.x;                         // multiple of 8
    int bid = blockIdx.x;
    int wid = (bid & 7) * (nwg >> 3) + (bid >> 3);
    int slot = wid / (NJT * KSPL);
    if (slot >= *n_slots) return;
    int rem = wid % (NJT * KSPL);
    int jt = rem / KSPL, split = rem % KSPL;
    int kbase = split * KCH;

    int e = slot_e[slot], row0 = slot_row0[slot], gbase = slot_gbase[slot];
    int cnt = counts[e];
    int pad_e = (cnt + 127) & ~127;

    __shared__ __align__(16) bf16 shm[65536];    // A: [0,32768) B: [32768,65536)

    int t = threadIdx.x;
    int lane = t & 63, wv = t >> 6;
    int wm = wv >> 2, wn = wv & 3;
    int lr = lane & 15, kq = lane >> 4;
    int bh = wn >> 1, bro = (wn & 1) * 64;

    // staging source offsets (elems), per (half, q-instr):
    //   row_local = wv*16 + q*8 + lane/8; granule g = (lane&7)^(lane>>3)
    int aoff[2][2]; int boff[2][2];
    const bf16* Abase = (MODE == 0) ? Xb : Ah;
    const bf16* Bbase = Bt + (size_t)e * N * K;
    int g8 = ((lane & 7) ^ (lane >> 3)) * 8;
    #pragma unroll
    for (int h = 0; h < 2; ++h)
        #pragma unroll
        for (int q = 0; q < 2; ++q) {
            int rloc = h*128 + wv*16 + q*8 + (lane >> 3);
            if (MODE == 0) {
                int tok = token_ids[gbase + row0 + rloc];
                aoff[h][q] = tok * DMODEL + g8;
            } else {
                aoff[h][q] = (gbase + row0 + rloc) * DFF + kbase + g8;
            }
            boff[h][q] = (jt*256 + rloc) * K + kbase + g8;
        }

    f32x4 acc[8][4] = {};
    bf16x8 breg[4][2];

    #define STAGE_A(S, H, T) do { int _t = ((T) < NT ? (T) : 0) * BK;                   \
        gload16(Abase + aoff[H][0] + _t, shm + (((S)*2+(H))*128 + wv*16    ) * BK);     \
        gload16(Abase + aoff[H][1] + _t, shm + (((S)*2+(H))*128 + wv*16 + 8) * BK); } while(0)
    #define STAGE_B(S, H, T) do { int _t = ((T) < NT ? (T) : 0) * BK;                           \
        gload16(Bbase + boff[H][0] + _t, shm + 32768 + (((S)*2+(H))*128 + wv*16    ) * BK);     \
        gload16(Bbase + boff[H][1] + _t, shm + 32768 + (((S)*2+(H))*128 + wv*16 + 8) * BK); } while(0)

    // prologue: T0 all 4 halves, T1 B halves; vmcnt(4) certifies T0 landed
    STAGE_A(0,0,0); STAGE_A(0,1,0); STAGE_B(0,0,0); STAGE_B(0,1,0);
    STAGE_B(1,0,1); STAGE_B(1,1,1);
    asm volatile("s_waitcnt vmcnt(4)" ::: "memory");
    __builtin_amdgcn_s_barrier();

    // one quadrant sub-step: load A-frags for quadrant Q, 16 MFMA
    #define LOAD_A(S, Q)                                                             \
        _Pragma("unroll") for (int mi = 0; mi < 2; ++mi)                             \
            _Pragma("unroll") for (int kk = 0; kk < 2; ++kk)                         \
                areg[mi][kk] = *(const bf16x8*)(shm +                                \
                    (((S)*2+wm)*128 + ((Q)*2+mi)*16 + lr) * BK +                     \
                    ((kk*4+kq) ^ (lr & 7)) * 8);
    #define MFMA_Q(Q)                                                                \
        __builtin_amdgcn_s_setprio(1);                                               \
        _Pragma("unroll") for (int mi = 0; mi < 2; ++mi)                             \
            _Pragma("unroll") for (int n = 0; n < 4; ++n)                            \
                _Pragma("unroll") for (int kk = 0; kk < 2; ++kk)                     \
                    acc[(Q)*2+mi][n] = __builtin_amdgcn_mfma_f32_16x16x32_bf16(      \
                        areg[mi][kk], breg[n][kk], acc[(Q)*2+mi][n], 0, 0, 0);       \
        __builtin_amdgcn_s_setprio(0);

    // merged phase: 2 quadrants, 2 half-tile stages, ONE barrier pair
    #define PHASE2(S, Q2, STAGE_CODE, DO_WAIT)                                       \
    {                                                                                \
        bf16x8 areg[2][2];                                                           \
        if ((Q2) == 0) {                                                             \
            _Pragma("unroll") for (int n = 0; n < 4; ++n)                            \
                _Pragma("unroll") for (int kk = 0; kk < 2; ++kk)                     \
                    breg[n][kk] = *(const bf16x8*)(shm + 32768 +                     \
                        (((S)*2+bh)*128 + bro + n*16 + lr) * BK +                    \
                        ((kk*4+kq) ^ (lr & 7)) * 8);                                 \
        }                                                                            \
        LOAD_A(S, (Q2)*2)                                                            \
        STAGE_CODE;                                                                  \
        asm volatile("" ::: "memory");                                               \
        __builtin_amdgcn_s_barrier();                                                \
        MFMA_Q((Q2)*2)                                                               \
        LOAD_A(S, (Q2)*2+1)                                                          \
        MFMA_Q((Q2)*2+1)                                                             \
        if (DO_WAIT) asm volatile("s_waitcnt vmcnt(4)" ::: "memory");                \
        asm volatile("" ::: "memory");                                               \
        __builtin_amdgcn_s_barrier();                                                \
    }

    for (int i = 0; i < NITER; ++i) {
        int TO = 2*i+1, TE2 = 2*i+2, TO2 = 2*i+3;
        PHASE2(0, 0, { STAGE_A(1,0,TO);  STAGE_A(1,1,TO);  }, 0)
        PHASE2(0, 1, { STAGE_B(0,0,TE2); STAGE_B(0,1,TE2); }, 1)
        PHASE2(1, 0, { STAGE_A(0,0,TE2); STAGE_A(0,1,TE2); }, 0)
        PHASE2(1, 1, { STAGE_B(1,0,TO2); STAGE_B(1,1,TO2); }, 1)
    }
    asm volatile("s_waitcnt vmcnt(0)" ::: "memory");   // drain tail junk stages
    #undef PHASE2
    #undef MFMA_Q
    #undef LOAD_A
    #undef STAGE_A
    #undef STAGE_B

    int lro = kq * 4;
    if (MODE == 0) {
        float bv[4];
        #pragma unroll
        for (int n = 0; n < 4; ++n)
            bv[n] = bias[e * DFF + jt*256 + wn*64 + n*16 + lr];
        #pragma unroll
        for (int m = 0; m < 8; ++m)
            #pragma unroll
            for (int reg = 0; reg < 4; ++reg) {
                int rl = wm*128 + m*16 + lro + reg;
                if (row0 + rl < pad_e) {
                    size_t hrow = (size_t)(gbase + row0 + rl);
                    #pragma unroll
                    for (int n = 0; n < 4; ++n) {
                        int col = jt*256 + wn*64 + n*16 + lr;
                        float v = acc[m][n][reg] + bv[n];
                        v = v / (1.0f + __expf(-v));       // silu
                        __builtin_nontemporal_store((bf16)v, &Hout[hrow * DFF + col]);
                    }
                }
            }
    } else {
        float bv[4];
        #pragma unroll
        for (int n = 0; n < 4; ++n)
            bv[n] = (split == 0) ? bias[e * DMODEL + jt*256 + wn*64 + n*16 + lr] : 0.0f;
        #pragma unroll
        for (int m = 0; m < 8; ++m)
            #pragma unroll
            for (int reg = 0; reg < 4; ++reg) {
                int rl = wm*128 + m*16 + lro + reg;
                if (row0 + rl < cnt) {
                    int pr = gbase + row0 + rl;
                    int tok = token_ids[pr];
                    float p = pair_p[pr];
                    #pragma unroll
                    for (int n = 0; n < 4; ++n) {
                        int col = jt*256 + wn*64 + n*16 + lr;
                        atomicAdd(Out + (size_t)tok * DMODEL + col, p * (acc[m][n][reg] + bv[n]));
                    }
                }
            }
    }
}

// ---------------- launch ----------------
extern "C" void kernel_launch(void* const* d_in, const int* in_sizes, int n_in,
                              void* d_out, int out_size, void* d_ws, size_t ws_size,
                              hipStream_t stream)
{
    const float* x  = (const float*)d_in[0];
    const float* gw = (const float*)d_in[1];
    const float* gb = (const float*)d_in[2];
    const float* w1 = (const float*)d_in[3];
    const float* b1 = (const float*)d_in[4];
    const float* w2 = (const float*)d_in[5];
    const float* b2 = (const float*)d_in[6];
    float* out = (float*)d_out;

    const size_t W1T_OFF = 0;
    const size_t W2T_OFF = 67108864;                       // 8*4096*1024*2
    const size_t H_OFF   = 134217728;
    const size_t RT_OFF  = H_OFF + (size_t)PAD_H * DFF * 2; // 278921216
    const size_t WS_NEEDED = RT_OFF + 274432;               // 279195648
    if (ws_size < WS_NEEDED) return;                        // fail clean

    char* ws = (char*)d_ws;
    bf16* w1t = (bf16*)(ws + W1T_OFF);
    bf16* w2t = (bf16*)(ws + W2T_OFF);
    bf16* xb  = (bf16*)(ws + W2T_OFF);          // aliases w2t: xb dead after gemm1
    bf16* h   = (bf16*)(ws + H_OFF);
    char* rt  = ws + RT_OFF;
    int*   counts    = (int*)(rt + 0);
    int*   seg_base  = (int*)(rt + 64);
    int*   cursor    = (int*)(rt + 128);
    int*   n_slots   = (int*)(rt + 192);
    int*   slot_e    = (int*)(rt + 256);
    int*   slot_row0 = (int*)(rt + 768);
    int*   slot_gbase= (int*)(rt + 1280);
    int2*  topk_i    = (int2*)(rt + 2048);
    float2* topk_p   = (float2*)(rt + 67584);
    int*   token_ids = (int*)(rt + 133120);
    float* pair_p    = (float*)(rt + 203776);

    hipMemsetAsync(rt, 0, 256, stream);                           // counts/cursor/n_slots
    hipMemsetAsync(token_ids, 0, PAD_IDX * sizeof(int), stream);
    hipMemsetAsync(out, 0, (size_t)TOKENS * DMODEL * sizeof(float), stream);

    transpose_cvt<<<dim3(DFF/64, DMODEL/64, NEXP), dim3(64, 4), 0, stream>>>(w1, w1t, DMODEL, DFF);

    gate_kernel<<<TOKENS * 64 / 256, 256, 0, stream>>>(x, gw, gb, counts, topk_i, topk_p, xb);
    build_slots<<<1, 128, 0, stream>>>(counts, seg_base, n_slots, slot_e, slot_row0, slot_gbase);
    scatter_kernel<<<TOKENS / 256, 256, 0, stream>>>(topk_i, topk_p, seg_base, cursor, token_ids, pair_p);

    moe_gemm<0><<<MAX_SLOTS * (DFF/256), 512, 0, stream>>>(
        xb, nullptr, w1t, b1, h, nullptr,
        token_ids, pair_p, slot_e, slot_row0, slot_gbase, n_slots, counts);

    // w2 transpose AFTER gemm1 so w2t can alias xb
    transpose_cvt<<<dim3(DMODEL/64, DFF/64, NEXP), dim3(64, 4), 0, stream>>>(w2, w2t, DFF, DMODEL);

    moe_gemm<1><<<MAX_SLOTS * (DMODEL/256) * 2, 512, 0, stream>>>(
        nullptr, h, w2t, b2, nullptr, out,
        token_ids, pair_p, slot_e, slot_row0, slot_gbase, n_slots, counts);
}